// Round 2
// baseline (503.355 us; speedup 1.0000x reference)
//
#include <hip/hip_runtime.h>

// LSSViewTransform: 1x1 conv (context channels only; mean(softmax)==1/64
// identity) + bilinear resize (32,88)->(432,496), half-pixel centers.

#define K_IN    256
#define C_CTX   128
#define C_DEPTH 64
#define H_IN    32
#define W_IN    88
#define POS     (H_IN * W_IN)     // 2816 = 44 * 64
#define H_OUT   432
#define W_OUT   496
#define XG      (W_OUT / 4)       // 124 float4 groups per output row
#define GPP     (XG * H_OUT)      // 53568 groups per (b,c) plane
#define NPLANE  (4 * C_CTX)       // 512 planes

#define KC      64                // k-chunk
#define BPOS    64                // positions per block
#define LROW    68                // padded LDS row stride (words): 68*4=272B,
                                  // 16B-aligned for ds_read_b128; 8-way bank
                                  // aliasing == the b128 1024B/128B floor.

// ---------------------------------------------------------------------------
// Kernel 1: ctx[b][c][pos] = (sum_i feat[b][i][pos]*Wc[64+c][i] + bc[64+c])/64
// Block: 256 thr = 4 waves, computes 64 positions x 64 channels.
//  - feat tile (64 pos x 64 k) staged global->reg->LDS (transposed to
//    [pos][k]) with next-chunk register prefetch overlapping compute.
//  - Each wave owns 16 wave-uniform channels -> W reads are s_load (free).
//  - feat read from HBM exactly once per c-half (2x total = 23 MB).
// ---------------------------------------------------------------------------
__global__ __launch_bounds__(256) void conv1x1_kernel(
    const float* __restrict__ feat, const float* __restrict__ Wc,
    const float* __restrict__ bc, float* __restrict__ ctx)
{
    __shared__ float fs[BPOS * LROW];   // 17.4 KB

    const int t       = threadIdx.x;
    const int posbase = blockIdx.x * BPOS;
    const int b       = blockIdx.z;
    const int wave    = __builtin_amdgcn_readfirstlane(t >> 6);
    const int cbase   = blockIdx.y * 64 + wave * 16;   // this wave's channels
    const int lane    = t & 63;

    const float* fb  = feat + (size_t)b * K_IN * POS + posbase;
    const int kl0 = t >> 4;          // 0..15  (k row within chunk, +16j)
    const int p0  = (t & 15) * 4;    // 0..60  (position group)

    // prefetch chunk 0: 4 float4 per thread, coalesced 256B per k-row
    float4 pre[4];
    #pragma unroll
    for (int j = 0; j < 4; ++j)
        pre[j] = *(const float4*)(fb + (size_t)(kl0 + 16 * j) * POS + p0);

    float acc[16];
    #pragma unroll
    for (int c = 0; c < 16; ++c) acc[c] = 0.f;

    const float* wbase = Wc + (size_t)(C_DEPTH + cbase) * K_IN;

    for (int kc = 0; kc < K_IN / KC; ++kc) {
        // scatter staged chunk into LDS (transpose to [pos][k])
        #pragma unroll
        for (int j = 0; j < 4; ++j) {
            int kl = kl0 + 16 * j;
            fs[(p0 + 0) * LROW + kl] = pre[j].x;
            fs[(p0 + 1) * LROW + kl] = pre[j].y;
            fs[(p0 + 2) * LROW + kl] = pre[j].z;
            fs[(p0 + 3) * LROW + kl] = pre[j].w;
        }
        __syncthreads();

        // prefetch next chunk while computing this one
        if (kc + 1 < K_IN / KC) {
            const float* fn = fb + (size_t)(kc + 1) * KC * POS;
            #pragma unroll
            for (int j = 0; j < 4; ++j)
                pre[j] = *(const float4*)(fn + (size_t)(kl0 + 16 * j) * POS + p0);
        }

        const float* wk = wbase + kc * KC;   // uniform -> scalar
        #pragma unroll
        for (int kk = 0; kk < KC; kk += 4) {
            float4 f = *(const float4*)&fs[lane * LROW + kk];
            #pragma unroll
            for (int c = 0; c < 16; ++c) {
                const float* w4 = wk + c * K_IN + kk;  // uniform addr -> s_load
                float a = acc[c];
                a = fmaf(f.x, w4[0], a);
                a = fmaf(f.y, w4[1], a);
                a = fmaf(f.z, w4[2], a);
                a = fmaf(f.w, w4[3], a);
                acc[c] = a;
            }
        }
        __syncthreads();
    }

    const float s = 1.0f / 64.0f;   // mean over softmax channels == 1/64
    #pragma unroll
    for (int c = 0; c < 16; ++c) {
        float v = (acc[c] + bc[C_DEPTH + cbase + c]) * s;
        ctx[(size_t)(b * C_CTX + cbase + c) * POS + posbase + lane] = v;
    }
}

// ---------------------------------------------------------------------------
// Kernel 2: bilinear resize, one thread per float4 of output row.
// src = (i + 0.5) * in/out - 0.5, edge clamp (== jax renormalized triangle).
// 4 consecutive outputs span <= 0.71 input px -> 3 taps/row suffice.
// ---------------------------------------------------------------------------
__global__ __launch_bounds__(256) void resize_kernel(
    const float* __restrict__ ctx, float* __restrict__ out)
{
    int g = blockIdx.x * blockDim.x + threadIdx.x;
    if (g >= GPP) return;
    int y  = g / XG;
    int xg = g - y * XG;
    int plane = blockIdx.y;                 // b*128 + c

    const float* p = ctx + (size_t)plane * POS;

    const float SCY = 32.0f / 432.0f;
    const float SCX = 88.0f / 496.0f;

    float sy  = (y + 0.5f) * SCY - 0.5f;
    float fyf = floorf(sy);
    float wy  = sy - fyf;
    int y0  = (int)fyf;
    int y0c = max(y0, 0);
    int y1c = min(y0 + 1, H_IN - 1);
    const float* r0 = p + y0c * W_IN;
    const float* r1 = p + y1c * W_IN;

    float sx0 = (4 * xg + 0.5f) * SCX - 0.5f;
    int xb = (int)floorf(sx0);

    float ry[3];
    #pragma unroll
    for (int tp = 0; tp < 3; ++tp) {
        int xt = min(max(xb + tp, 0), W_IN - 1);
        float a = r0[xt];
        float b = r1[xt];
        ry[tp] = a + wy * (b - a);          // y-interpolated row values
    }

    float o[4];
    #pragma unroll
    for (int j = 0; j < 4; ++j) {
        float s  = (4 * xg + j + 0.5f) * SCX - 0.5f;
        float fs = floorf(s);
        float fx = s - fs;
        int tp = (int)fs - xb;              // 0 or 1 (monotone fp, safe)
        o[j] = ry[tp] + fx * (ry[tp + 1] - ry[tp]);
    }

    size_t oidx = ((size_t)plane * H_OUT + y) * W_OUT + 4 * xg;
    float4 v = {o[0], o[1], o[2], o[3]};
    *(float4*)(out + oidx) = v;
}

extern "C" void kernel_launch(void* const* d_in, const int* in_sizes, int n_in,
                              void* d_out, int out_size, void* d_ws, size_t ws_size,
                              hipStream_t stream) {
    const float* feat = (const float*)d_in[0];   // (4, 256, 32, 88)
    const float* Wc   = (const float*)d_in[1];   // (192, 256)
    const float* bc   = (const float*)d_in[2];   // (192,)
    float* out = (float*)d_out;                  // (4, 128, 432, 496)
    float* ctx = (float*)d_ws;                   // (4, 128, 2816) = 5.77 MB

    dim3 b1(256);
    dim3 g1(POS / BPOS, C_CTX / 64, 4);          // (44, 2, 4) = 352 blocks
    conv1x1_kernel<<<g1, b1, 0, stream>>>(feat, Wc, bc, ctx);

    dim3 b2(256);
    dim3 g2((GPP + 255) / 256, NPLANE);          // (210, 512)
    resize_kernel<<<g2, b2, 0, stream>>>(ctx, out);
}

// Round 4
// 452.032 us; speedup vs baseline: 1.1135x; 1.1135x over previous
//
#include <hip/hip_runtime.h>

// LSSViewTransform: 1x1 conv (context channels only; mean(softmax)==1/64
// identity) + bilinear resize (32,88)->(432,496), half-pixel centers.

#define K_IN    256
#define C_CTX   128
#define C_DEPTH 64
#define H_IN    32
#define W_IN    88
#define POS     (H_IN * W_IN)     // 2816 = 44 * 64
#define H_OUT   432
#define W_OUT   496
#define XG      (W_OUT / 4)       // 124 float4 groups per output row
#define GPP     (XG * H_OUT)      // 53568 groups per (b,c) plane
#define NPLANE  (4 * C_CTX)       // 512 planes
#define KC      64                // k-chunk

typedef float f32x4 __attribute__((ext_vector_type(4)));  // native vec for
                                                          // nontemporal store

// ---------------------------------------------------------------------------
// Kernel 1: ctx[b][c][pos] = (sum_i feat[b][i][pos]*Wc[64+c][i] + bc[64+c])/64
// LDS-LDS register-blocked GEMM. Block = 256 thr, tile 64 pos x 64 ch.
//  - As: [k][pos] natural layout, direct coalesced copy (no transpose).
//  - Bs: [k][ch], transposed at stage time (4-way b32 write conflicts only).
//  - Compute: per k, 2x ds_read_b128 + 16 FMA; lane addresses vary only in
//    low bits -> conflict-free reads (a: 8 quads 2-way, b: pure broadcast).
// ---------------------------------------------------------------------------
__global__ __launch_bounds__(256) void conv1x1_kernel(
    const float* __restrict__ feat, const float* __restrict__ Wc,
    const float* __restrict__ bc, float* __restrict__ ctx)
{
    __shared__ float As[KC * 64];   // [k][pos]  16 KB
    __shared__ float Bs[KC * 64];   // [k][ch]   16 KB

    const int t       = threadIdx.x;
    const int posbase = blockIdx.x * 64;
    const int cbase   = blockIdx.y * 64;
    const int b       = blockIdx.z;

    const int pg = t & 15;          // this thread's pos group (4 pos)
    const int cg = t >> 4;          // this thread's ch group (4 ch)

    const float* fb = feat + (size_t)b * K_IN * POS + posbase;
    const float* wb = Wc + (size_t)(C_DEPTH + cbase) * K_IN;

    float acc[4][4];
    #pragma unroll
    for (int i = 0; i < 4; ++i)
        #pragma unroll
        for (int j = 0; j < 4; ++j) acc[i][j] = 0.f;

    for (int kc = 0; kc < K_IN / KC; ++kc) {
        // ---- stage A: 64k x 64pos, coalesced 256B per k-row ----
        #pragma unroll
        for (int j = 0; j < 4; ++j) {
            int k  = (t >> 4) + 16 * j;
            int p4 = (t & 15) * 4;
            *(float4*)&As[k * 64 + p4] =
                *(const float4*)(fb + (size_t)(kc * KC + k) * POS + p4);
        }
        // ---- stage B transposed: Wc[ch][k] -> Bs[k][ch] ----
        #pragma unroll
        for (int j = 0; j < 4; ++j) {
            int ch = t >> 2;
            int k  = (t & 3) * 4 + 16 * j;
            float4 w = *(const float4*)(wb + (size_t)ch * K_IN + kc * KC + k);
            Bs[(k + 0) * 64 + ch] = w.x;
            Bs[(k + 1) * 64 + ch] = w.y;
            Bs[(k + 2) * 64 + ch] = w.z;
            Bs[(k + 3) * 64 + ch] = w.w;
        }
        __syncthreads();

        // ---- compute: 64 k-steps, 2 b128 + 16 FMA each ----
        #pragma unroll 8
        for (int k = 0; k < KC; ++k) {
            float4 a = *(const float4*)&As[k * 64 + pg * 4];
            float4 w = *(const float4*)&Bs[k * 64 + cg * 4];
            acc[0][0] = fmaf(a.x, w.x, acc[0][0]);
            acc[1][0] = fmaf(a.y, w.x, acc[1][0]);
            acc[2][0] = fmaf(a.z, w.x, acc[2][0]);
            acc[3][0] = fmaf(a.w, w.x, acc[3][0]);
            acc[0][1] = fmaf(a.x, w.y, acc[0][1]);
            acc[1][1] = fmaf(a.y, w.y, acc[1][1]);
            acc[2][1] = fmaf(a.z, w.y, acc[2][1]);
            acc[3][1] = fmaf(a.w, w.y, acc[3][1]);
            acc[0][2] = fmaf(a.x, w.z, acc[0][2]);
            acc[1][2] = fmaf(a.y, w.z, acc[1][2]);
            acc[2][2] = fmaf(a.z, w.z, acc[2][2]);
            acc[3][2] = fmaf(a.w, w.z, acc[3][2]);
            acc[0][3] = fmaf(a.x, w.w, acc[0][3]);
            acc[1][3] = fmaf(a.y, w.w, acc[1][3]);
            acc[2][3] = fmaf(a.z, w.w, acc[2][3]);
            acc[3][3] = fmaf(a.w, w.w, acc[3][3]);
        }
        __syncthreads();
    }

    const float s = 1.0f / 64.0f;   // mean over softmax channels == 1/64
    #pragma unroll
    for (int j = 0; j < 4; ++j) {
        int ch = cbase + 4 * cg + j;
        float bb = bc[C_DEPTH + ch];
        float4 r;
        r.x = (acc[0][j] + bb) * s;
        r.y = (acc[1][j] + bb) * s;
        r.z = (acc[2][j] + bb) * s;
        r.w = (acc[3][j] + bb) * s;
        *(float4*)(ctx + (size_t)(b * C_CTX + ch) * POS + posbase + 4 * pg) = r;
    }
}

// ---------------------------------------------------------------------------
// Kernel 2: bilinear resize, one thread per float4 of output row.
// src = (i + 0.5) * in/out - 0.5, edge clamp (== jax renormalized triangle).
// Nontemporal stores: output is 438.8 MB write-once, skip L2 write-allocate.
// ---------------------------------------------------------------------------
__global__ __launch_bounds__(256) void resize_kernel(
    const float* __restrict__ ctx, float* __restrict__ out)
{
    int g = blockIdx.x * blockDim.x + threadIdx.x;
    if (g >= GPP) return;
    int y  = g / XG;
    int xg = g - y * XG;
    int plane = blockIdx.y;                 // b*128 + c

    const float* p = ctx + (size_t)plane * POS;

    const float SCY = 32.0f / 432.0f;
    const float SCX = 88.0f / 496.0f;

    float sy  = (y + 0.5f) * SCY - 0.5f;
    float fyf = floorf(sy);
    float wy  = sy - fyf;
    int y0  = (int)fyf;
    int y0c = max(y0, 0);
    int y1c = min(y0 + 1, H_IN - 1);
    const float* r0 = p + y0c * W_IN;
    const float* r1 = p + y1c * W_IN;

    float sx0 = (4 * xg + 0.5f) * SCX - 0.5f;
    int xb = (int)floorf(sx0);

    float ry[3];
    #pragma unroll
    for (int tp = 0; tp < 3; ++tp) {
        int xt = min(max(xb + tp, 0), W_IN - 1);
        float a = r0[xt];
        float b = r1[xt];
        ry[tp] = a + wy * (b - a);          // y-interpolated row values
    }

    float o[4];
    #pragma unroll
    for (int j = 0; j < 4; ++j) {
        float s  = (4 * xg + j + 0.5f) * SCX - 0.5f;
        float fs = floorf(s);
        float fx = s - fs;
        int tp = (int)fs - xb;              // 0 or 1 (monotone fp, safe)
        o[j] = ry[tp] + fx * (ry[tp + 1] - ry[tp]);
    }

    size_t oidx = ((size_t)plane * H_OUT + y) * W_OUT + 4 * xg;
    f32x4 v = {o[0], o[1], o[2], o[3]};
    __builtin_nontemporal_store(v, (f32x4*)(out + oidx));
}

extern "C" void kernel_launch(void* const* d_in, const int* in_sizes, int n_in,
                              void* d_out, int out_size, void* d_ws, size_t ws_size,
                              hipStream_t stream) {
    const float* feat = (const float*)d_in[0];   // (4, 256, 32, 88)
    const float* Wc   = (const float*)d_in[1];   // (192, 256)
    const float* bc   = (const float*)d_in[2];   // (192,)
    float* out = (float*)d_out;                  // (4, 128, 432, 496)
    float* ctx = (float*)d_ws;                   // (4, 128, 2816) = 5.77 MB

    dim3 b1(256);
    dim3 g1(POS / 64, C_CTX / 64, 4);            // (44, 2, 4) = 352 blocks
    conv1x1_kernel<<<g1, b1, 0, stream>>>(feat, Wc, bc, ctx);

    dim3 b2(256);
    dim3 g2((GPP + 255) / 256, NPLANE);          // (210, 512)
    resize_kernel<<<g2, b2, 0, stream>>>(ctx, out);
}